// Round 2
// baseline (521.219 us; speedup 1.0000x reference)
//
#include <hip/hip_runtime.h>
#include <stdint.h>

typedef unsigned short u16;
typedef unsigned int u32;
typedef __bf16 bf16x8 __attribute__((ext_vector_type(8)));
typedef float f32x4 __attribute__((ext_vector_type(4)));

#define N_ATOMS 512
#define BDIM 14
#define BB 196          // 14*14
#define FDIM 128
#define HROW 7168       // 512*14
#define NPAIR 130816
#define NPBLK (NPAIR / 128)   // 1022 pair blocks

// frag-ordered bf16 weights in ws (u16 element offsets)
#define OFF_W1F   0         // 8 ks * 16 nt * 512
#define OFF_W2F   65536     // 8 ks * 13 nt * 512
#define OFF_WO1F  118784    // 12 ks * 16 nt * 512
#define OFF_WO2F  217088    // 8 ks * 13 nt * 512
#define WS_ELEMS  270336

__device__ __forceinline__ float b2f(u16 u) {
    union { u32 u; float f; } c; c.u = ((u32)u) << 16; return c.f;
}
__device__ __forceinline__ u16 fb(float f) {   // fp32 -> bf16 bits, RTNE
    union { float f; u32 u; } c; c.f = f;
    u32 r = c.u + 0x7fff + ((c.u >> 16) & 1);
    return (u16)(r >> 16);
}
__device__ __forceinline__ bf16x8 ld16b(const u16* p) {
    return *(const bf16x8*)(const void*)p;
}
// load 8 fp32 (32B, aligned) and convert to a bf16x8 fragment
__device__ __forceinline__ bf16x8 ldcvt8(const float* p) {
    const float4 a = *(const float4*)(const void*)p;
    const float4 b = *(const float4*)(const void*)(p + 4);
    bf16x8 r;
    r[0] = (__bf16)a.x; r[1] = (__bf16)a.y; r[2] = (__bf16)a.z; r[3] = (__bf16)a.w;
    r[4] = (__bf16)b.x; r[5] = (__bf16)b.y; r[6] = (__bf16)b.z; r[7] = (__bf16)b.w;
    return r;
}

// ---- reorder fp32 weights into bf16 MFMA fragment order:
// Wf[ks][nt][lane][j] = bf16(W[ks*32 + (lane>>4)*8 + j][nt*16 + (lane&15)]), zero-padded cols
__global__ void prep_kernel(const float* __restrict__ W1, const float* __restrict__ W2,
                            const float* __restrict__ Wo1, const float* __restrict__ Wo2,
                            u16* __restrict__ ws) {
    int gid = blockIdx.x * 256 + threadIdx.x;
    const float* src; int idx, NT, Ncols, Nreal;
    if (gid < OFF_W2F)       { idx = gid;             src = W1;  NT = 16; Ncols = 256; Nreal = 256; }
    else if (gid < OFF_WO1F) { idx = gid - OFF_W2F;   src = W2;  NT = 13; Ncols = 196; Nreal = 196; }
    else if (gid < OFF_WO2F) { idx = gid - OFF_WO1F;  src = Wo1; NT = 16; Ncols = 256; Nreal = 256; }
    else                     { idx = gid - OFF_WO2F;  src = Wo2; NT = 13; Ncols = 196; Nreal = 196; }
    int jj   = idx & 7;
    int lane = (idx >> 3) & 63;
    int tile = idx >> 9;
    int nt = tile % NT;
    int ks = tile / NT;
    int k = ks * 32 + ((lane >> 4) << 3) + jj;
    int n = nt * 16 + (lane & 15);
    ws[gid] = (n < Nreal) ? fb(src[k * Ncols + n]) : (u16)0;
}

// ---- fused MLP + scatter. blocks [0,1022): 128 pairs each; blocks [1022,1026): 128 diag rows.
__global__ __launch_bounds__(256, 2)
void ham_main(const float* __restrict__ nodes, const float* __restrict__ edges,
              const float* __restrict__ atomb, const float* __restrict__ ovl,
              const float* __restrict__ b1v, const float* __restrict__ b2v,
              const float* __restrict__ bo1, const float* __restrict__ bo2,
              const int* __restrict__ pair_i, const int* __restrict__ pair_j,
              const u16* __restrict__ ws, float* __restrict__ out)
{
    // H tile: 128 rows x 264 (256 hidden + 8 pad) bf16 = 66 KB  -> 2 blocks/CU
    __shared__ u16 sH[128 * 264];
    __shared__ int sI[128], sJ[128];
    const int tid = threadIdx.x;
    const int w = tid >> 6, lane = tid & 63;
    const int q = lane >> 4, l15 = lane & 15;
    const int bid = blockIdx.x;
    const bool isPair = bid < NPBLK;
    const int wr = w >> 1, wc = w & 1;   // stage-1 wave grid: hidden-half x row-half

    const float* rowA[4];   // k segment 0 (nodes_i / nodes_n)
    const float* rowB[4];   // k segment 1 (nodes_j / edges_nn)
    const float* rowE[4];   // k segment 2 (edges_ij, pair only)
    int KS1;
    const u16 *WAf, *WBf;
    const float *bias1, *bias2;

    if (isPair) {
        const int pbase = bid * 128;
        KS1 = 12; WAf = ws + OFF_WO1F; WBf = ws + OFF_WO2F; bias1 = bo1; bias2 = bo2;
        if (tid < 128) { int p = pbase + tid; sI[tid] = pair_i[p]; sJ[tid] = pair_j[p]; }
        #pragma unroll
        for (int pp = 0; pp < 4; ++pp) {
            int p = pbase + wc * 64 + pp * 16 + l15;
            int i = pair_i[p], j = pair_j[p];
            rowA[pp] = nodes + (size_t)i * FDIM;
            rowB[pp] = nodes + (size_t)j * FDIM;
            rowE[pp] = edges + ((size_t)i * N_ATOMS + j) * FDIM;
        }
    } else {
        const int nbase = (bid - NPBLK) * 128;
        KS1 = 8; WAf = ws + OFF_W1F; WBf = ws + OFF_W2F; bias1 = b1v; bias2 = b2v;
        #pragma unroll
        for (int pp = 0; pp < 4; ++pp) {
            int nn = nbase + wc * 64 + pp * 16 + l15;
            rowA[pp] = nodes + (size_t)nn * FDIM;
            rowB[pp] = edges + ((size_t)nn * N_ATOMS + nn) * FDIM;
            rowE[pp] = rowB[pp];
        }
    }

    // ======== stage 1: D[hidden][row] = W^T * X^T  (A = frag-order W, B = gathered X rows)
    f32x4 acc[8][4];
    #pragma unroll
    for (int a = 0; a < 8; ++a)
        #pragma unroll
        for (int b = 0; b < 4; ++b)
            acc[a][b] = (f32x4){0.f, 0.f, 0.f, 0.f};

    for (int ks = 0; ks < KS1; ++ks) {
        const int seg = ks >> 2;
        const int koff = (ks & 3) * 32 + q * 8;
        bf16x8 bfr[4];
        #pragma unroll
        for (int pp = 0; pp < 4; ++pp) {
            const float* base = (seg == 0) ? rowA[pp] : (seg == 1) ? rowB[pp] : rowE[pp];
            bfr[pp] = ldcvt8(base + koff);
        }
        const u16* ap = WAf + ((size_t)((ks * 16 + wr * 8) * 64 + lane)) * 8;
        #pragma unroll
        for (int hh = 0; hh < 8; ++hh) {
            bf16x8 afr = ld16b(ap + (size_t)hh * 512);
            #pragma unroll
            for (int pp = 0; pp < 4; ++pp)
                acc[hh][pp] = __builtin_amdgcn_mfma_f32_16x16x32_bf16(afr, bfr[pp], acc[hh][pp], 0, 0, 0);
        }
    }

    // bias + SiLU, write H[row][hidden] bf16 (lane holds 4 consecutive hidden -> one 8B write)
    #pragma unroll
    for (int hh = 0; hh < 8; ++hh) {
        const int h0 = wr * 128 + hh * 16 + q * 4;
        const float bb0 = bias1[h0], bb1 = bias1[h0 + 1];
        const float bb2 = bias1[h0 + 2], bb3 = bias1[h0 + 3];
        #pragma unroll
        for (int pp = 0; pp < 4; ++pp) {
            const int row = wc * 64 + pp * 16 + l15;
            float x0 = acc[hh][pp][0] + bb0, x1 = acc[hh][pp][1] + bb1;
            float x2 = acc[hh][pp][2] + bb2, x3 = acc[hh][pp][3] + bb3;
            float s0 = x0 / (1.f + __expf(-x0)), s1 = x1 / (1.f + __expf(-x1));
            float s2 = x2 / (1.f + __expf(-x2)), s3 = x3 / (1.f + __expf(-x3));
            uint2 pk;
            pk.x = (u32)fb(s0) | ((u32)fb(s1) << 16);
            pk.y = (u32)fb(s2) | ((u32)fb(s3) << 16);
            *(uint2*)(void*)&sH[row * 264 + h0] = pk;
        }
    }
    __syncthreads();

    // ======== stage 2: D[row][e] = H * W2  (A = H from LDS, B = frag-order W2, N padded to 208)
    f32x4 acc2[2][13];
    #pragma unroll
    for (int m = 0; m < 2; ++m)
        #pragma unroll
        for (int n = 0; n < 13; ++n)
            acc2[m][n] = (f32x4){0.f, 0.f, 0.f, 0.f};

    for (int ks = 0; ks < 8; ++ks) {
        bf16x8 a2[2];
        #pragma unroll
        for (int mm = 0; mm < 2; ++mm) {
            const int row = w * 32 + mm * 16 + l15;
            a2[mm] = ld16b(&sH[row * 264 + ks * 32 + q * 8]);
        }
        const u16* bp = WBf + ((size_t)((ks * 13) * 64 + lane)) * 8;
        #pragma unroll
        for (int nt = 0; nt < 13; ++nt) {
            bf16x8 bfr = ld16b(bp + (size_t)nt * 512);
            acc2[0][nt] = __builtin_amdgcn_mfma_f32_16x16x32_bf16(a2[0], bfr, acc2[0][nt], 0, 0, 0);
            acc2[1][nt] = __builtin_amdgcn_mfma_f32_16x16x32_bf16(a2[1], bfr, acc2[1][nt], 0, 0, 0);
        }
    }
    __syncthreads();   // all H reads done; reuse sH as Out tile [128][196] bf16

    u16* sOut = sH;
    #pragma unroll
    for (int nt = 0; nt < 13; ++nt) {
        const int e = nt * 16 + l15;
        if (e < BB) {
            const float be = bias2[e];
            #pragma unroll
            for (int mm = 0; mm < 2; ++mm) {
                const int pr = w * 32 + mm * 16 + q * 4;
                #pragma unroll
                for (int r = 0; r < 4; ++r)
                    sOut[(pr + r) * BB + e] = fb(acc2[mm][nt][r] + be);
            }
        }
    }
    __syncthreads();

    if (isPair) {
        const int pbase = bid * 128;
        // add overlap blocks (coalesced float2 reads, bf16 round-trip err << threshold)
        const float* src = ovl + (size_t)pbase * BB;
        for (int idx = tid; idx < 12544; idx += 256) {
            const int off = idx * 2;
            const float2 a = *(const float2*)(const void*)(src + off);
            u32 h = *(u32*)(void*)(sOut + off);
            float lo = b2f((u16)h) + a.x;
            float hi = b2f((u16)(h >> 16)) + a.y;
            *(u32*)(void*)(sOut + off) = (u32)fb(lo) | ((u32)fb(hi) << 16);
        }
        __syncthreads();
        // direct blocks H[i*14+a][j*14+b]: fixed a -> consecutive pairs are contiguous cols
        for (int u = tid; u < 12544; u += 256) {
            const int a = u / 896;
            const int r = u - a * 896;
            const int pl = r / 7;
            const int c2 = (r - pl * 7) * 2;
            const int i = sI[pl], j = sJ[pl];
            u32 v = *(const u32*)(const void*)(sOut + pl * BB + a * 14 + c2);
            float2 o; o.x = b2f((u16)v); o.y = b2f((u16)(v >> 16));
            size_t addr = (size_t)(i * 14 + a) * HROW + j * 14 + c2;
            *(float2*)(void*)(out + addr) = o;
        }
        // transposed blocks H[j*14+b][i*14+a]
        for (int u = tid; u < 12544; u += 256) {
            const int pl = u / 98;
            const int r = u - pl * 98;
            const int b = r / 7;
            const int a2i = (r - b * 7) * 2;
            const int i = sI[pl], j = sJ[pl];
            float2 o;
            o.x = b2f(sOut[pl * BB + a2i * 14 + b]);
            o.y = b2f(sOut[pl * BB + (a2i + 1) * 14 + b]);
            size_t addr = (size_t)(j * 14 + b) * HROW + i * 14 + a2i;
            *(float2*)(void*)(out + addr) = o;
        }
    } else {
        const int nbase = (bid - NPBLK) * 128;
        const float* src = atomb + (size_t)nbase * BB;
        for (int idx = tid; idx < 12544; idx += 256) {
            const int off = idx * 2;
            const float2 a = *(const float2*)(const void*)(src + off);
            u32 h = *(u32*)(void*)(sOut + off);
            float lo = b2f((u16)h) + a.x;
            float hi = b2f((u16)(h >> 16)) + a.y;
            *(u32*)(void*)(sOut + off) = (u32)fb(lo) | ((u32)fb(hi) << 16);
        }
        __syncthreads();
        for (int u = tid; u < 12544; u += 256) {
            const int a = u / 896;
            const int r = u - a * 896;
            const int pl = r / 7;
            const int c2 = (r - pl * 7) * 2;
            const int nn = nbase + pl;
            u32 v = *(const u32*)(const void*)(sOut + pl * BB + a * 14 + c2);
            float2 o; o.x = b2f((u16)v); o.y = b2f((u16)(v >> 16));
            size_t addr = (size_t)(nn * 14 + a) * HROW + nn * 14 + c2;
            *(float2*)(void*)(out + addr) = o;
        }
    }
}

extern "C" void kernel_launch(void* const* d_in, const int* in_sizes, int n_in,
                              void* d_out, int out_size, void* d_ws, size_t ws_size,
                              hipStream_t stream) {
    const float* nodes = (const float*)d_in[0];
    const float* edges = (const float*)d_in[1];
    const float* atomb = (const float*)d_in[2];
    const float* ovl   = (const float*)d_in[3];
    const float* W1    = (const float*)d_in[4];
    const float* b1    = (const float*)d_in[5];
    const float* W2    = (const float*)d_in[6];
    const float* b2    = (const float*)d_in[7];
    const float* Wo1   = (const float*)d_in[8];
    const float* bo1   = (const float*)d_in[9];
    const float* Wo2   = (const float*)d_in[10];
    const float* bo2   = (const float*)d_in[11];
    const int* pi      = (const int*)d_in[12];
    const int* pj      = (const int*)d_in[13];
    u16* ws    = (u16*)d_ws;
    float* out = (float*)d_out;

    prep_kernel<<<WS_ELEMS / 256, 256, 0, stream>>>(W1, W2, Wo1, Wo2, ws);
    ham_main<<<NPBLK + N_ATOMS / 128, 256, 0, stream>>>(nodes, edges, atomb, ovl,
                                                        b1, b2, bo1, bo2, pi, pj, ws, out);
}